// Round 15
// baseline (125.319 us; speedup 1.0000x reference)
//
#include <hip/hip_runtime.h>
#include <hip/hip_bf16.h>
#include <math.h>

#define BB 2
#define CC 256
#define GG 32
#define NN 4096
#define EPSF 1e-6f
#define JSPLIT 8
#define JBLK (NN / JSPLIT)   // 512 j per block
#define CH 32                // j chunk
#define NT (JBLK / CH)       // 16 chunks
#define QTILE 128            // queries per attn block (4 waves x 32)
#define ITILE 16             // i-rows per fused out block (2 blocks/CU)
#define LOG2E 1.4426950408889634f

typedef _Float16 f16x8 __attribute__((ext_vector_type(8)));
typedef float f32x4 __attribute__((ext_vector_type(4)));
typedef float f32x16 __attribute__((ext_vector_type(16)));

static __device__ __forceinline__ unsigned short f2h_bits(float f) {
    _Float16 h = (_Float16)f;
    return __builtin_bit_cast(unsigned short, h);
}
static __device__ __forceinline__ unsigned pkh2(float a, float b) {
    return __builtin_bit_cast(unsigned, __builtin_amdgcn_cvt_pkrtz(a, b));
}
static __device__ __forceinline__ void gload16(const void* g, void* l) {
    __builtin_amdgcn_global_load_lds(
        (const __attribute__((address_space(1))) void*)g,
        (__attribute__((address_space(3))) void*)l, 16, 0, 0);
}

// ------- Kernel A: fused weight->fp16 conversion (blocks 0..255) + GN partials (256..511) -------
__global__ __launch_bounds__(256) void prep_gn_kernel(
    const float* __restrict__ wq, const float* __restrict__ wk,
    const float* __restrict__ wv, const float* __restrict__ wp,
    unsigned short* __restrict__ w16,
    const float* __restrict__ x, float2* __restrict__ part)
{
    __shared__ float red[8];
    int id = blockIdx.x;
    int t  = threadIdx.x;
    if (id < 256) {
        int m = id >> 6;
        const float* src = (m == 0) ? wq : (m == 1) ? wk : (m == 2) ? wv : wp;
        float scale = (m == 0) ? 0.0625f * LOG2E : 1.0f;
        int idx = (id & 63) * 256 + t;   // unit = 4 floats
        float4 v = ((const float4*)src)[idx];
        union { _Float16 h[4]; uint2 u; } pk;
        pk.h[0] = (_Float16)(v.x * scale);
        pk.h[1] = (_Float16)(v.y * scale);
        pk.h[2] = (_Float16)(v.z * scale);
        pk.h[3] = (_Float16)(v.w * scale);
        *(uint2*)(w16 + (size_t)m * CC * CC + (size_t)idx * 4) = pk.u;
    } else {
        int rem = id - 256;
        int g = rem & 31, p = (rem >> 5) & 3, b = rem >> 7;
        const float* base = x + ((size_t)b * CC + (size_t)g * 8) * NN + (size_t)p * 8192;
        float s = 0.f, ss = 0.f;
        for (int idx = t; idx < 2048; idx += 256) {
            float4 v4 = ((const float4*)base)[idx];
            s  += v4.x + v4.y + v4.z + v4.w;
            ss += v4.x*v4.x + v4.y*v4.y + v4.z*v4.z + v4.w*v4.w;
        }
        for (int off = 32; off; off >>= 1) {
            s  += __shfl_down(s,  off);
            ss += __shfl_down(ss, off);
        }
        int wid = t >> 6;
        if ((t & 63) == 0) { red[wid*2] = s; red[wid*2+1] = ss; }
        __syncthreads();
        if (t == 0) {
            part[(b*GG + g)*4 + p] = make_float2(red[0]+red[2]+red[4]+red[6],
                                                 red[1]+red[3]+red[5]+red[7]);
        }
    }
}

// ------------- Kernel B: fused GN-apply + q/k/v projections, 16-row tiles (2 blocks/CU) -------------
__global__ __launch_bounds__(256) void proj_qkv_kernel(
    const float* __restrict__ x, const float* __restrict__ sc,
    const float* __restrict__ bi, const float2* __restrict__ part,
    const unsigned short* __restrict__ w16,
    const float* __restrict__ bq, const float* __restrict__ bk,
    const float* __restrict__ bv,
    unsigned short* __restrict__ qT, unsigned short* __restrict__ kT,
    unsigned short* __restrict__ vC)
{
    int b  = blockIdx.y;
    int i0 = blockIdx.x * 16;
    int t  = threadIdx.x;
    __shared__ unsigned short htile[16 * 256];   // 8 KB, swizzled
    __shared__ float s_mean[GG], s_rstd[GG], s_sc[CC], s_bi[CC];
    if (t < GG) {
        float2 p0 = part[(b*GG + t)*4 + 0];
        float2 p1 = part[(b*GG + t)*4 + 1];
        float2 p2 = part[(b*GG + t)*4 + 2];
        float2 p3 = part[(b*GG + t)*4 + 3];
        float S  = p0.x + p1.x + p2.x + p3.x;
        float SS = p0.y + p1.y + p2.y + p3.y;
        float mean = S / 32768.f;
        float var  = SS / 32768.f - mean * mean;
        s_mean[t] = mean;
        s_rstd[t] = rsqrtf(var + EPSF);
    }
    s_sc[t] = sc[t];
    s_bi[t] = bi[t];
    __syncthreads();

    // fill: one 4x4 quad-tile per thread (16 rows x 256 c total)
    char* hw = (char*)htile;
    {
        int nq = (t & 3) * 4;
        int c0 = (t >> 2) * 4;
        float4 xr[4];
        float aa[4], dd[4];
        #pragma unroll
        for (int e = 0; e < 4; e++) {
            int c = c0 + e;
            xr[e] = *(const float4*)(x + ((size_t)b*CC + c)*NN + i0 + nq);
            aa[e] = s_rstd[c >> 3] * s_sc[c];
            dd[e] = s_bi[c] - s_mean[c >> 3] * aa[e];
        }
        #pragma unroll
        for (int j = 0; j < 4; j++) {
            int row = nq + j;
            union { _Float16 h[4]; uint2 u; } pk;
            pk.h[0] = (_Float16)(((const float*)&xr[0])[j] * aa[0] + dd[0]);
            pk.h[1] = (_Float16)(((const float*)&xr[1])[j] * aa[1] + dd[1]);
            pk.h[2] = (_Float16)(((const float*)&xr[2])[j] * aa[2] + dd[2]);
            pk.h[3] = (_Float16)(((const float*)&xr[3])[j] * aa[3] + dd[3]);
            int off = row*512 + (((c0 >> 3) ^ (row & 7)) << 4) + (c0 & 7) * 2;
            *(uint2*)(hw + off) = pk.u;
        }
    }
    __syncthreads();

    int lane = t & 63, w = t >> 6;
    int col = lane & 15, grp = lane >> 4;
    const char* hr = (const char*)htile;
    int rowc = col;   // A-tile row for MFMA fragments (16 rows)

    // q, k: wave w owns o-subtile ot*64 + w*16
    #pragma unroll
    for (int p = 0; p < 2; p++) {
        const unsigned short* wgt = w16 + (size_t)p * CC * CC;
        const float* bias = p ? bk : bq;
        unsigned short* outp = (p ? kT : qT) + (size_t)b * NN * CC;
        float osc = p ? 1.0f : 0.0625f * LOG2E;
        #pragma unroll
        for (int ot = 0; ot < 4; ot++) {
            int ow = ot * 64 + w * 16;
            f32x4 acc = (f32x4){0.f,0.f,0.f,0.f};
            #pragma unroll
            for (int ck = 0; ck < 8; ck++) {
                f16x8 af = *(const f16x8*)(wgt + (size_t)(ow + col)*CC + ck*32 + grp*8);
                f16x8 bf = *(const f16x8*)(hr + rowc*512 + (((ck*4 + grp) ^ (rowc & 7)) << 4));
                acc = __builtin_amdgcn_mfma_f32_16x16x32_f16(af, bf, acc, 0, 0, 0);
            }
            int obase = ow + grp * 4;
            float b0 = bias[obase]*osc, b1 = bias[obase+1]*osc,
                  b2 = bias[obase+2]*osc, b3 = bias[obase+3]*osc;
            int i = i0 + col;
            union { _Float16 h[4]; uint2 u; } pk;
            pk.h[0] = (_Float16)(acc[0] + b0);
            pk.h[1] = (_Float16)(acc[1] + b1);
            pk.h[2] = (_Float16)(acc[2] + b2);
            pk.h[3] = (_Float16)(acc[3] + b3);
            *(uint2*)(outp + (size_t)i*CC + obase) = pk.u;
        }
    }
    // v: wave w owns o-group w (64 outputs), all 16 rows
    {
        const unsigned short* wgt = w16 + (size_t)2 * CC * CC;
        unsigned short* outp = vC + (size_t)b * CC * NN;
        int og = w;
        f32x4 acc[4];
        #pragma unroll
        for (int ot = 0; ot < 4; ot++) acc[ot] = (f32x4){0.f,0.f,0.f,0.f};
        #pragma unroll
        for (int ck = 0; ck < 8; ck++) {
            f16x8 af = *(const f16x8*)(hr + rowc*512 + (((ck*4 + grp) ^ (rowc & 7)) << 4));
            #pragma unroll
            for (int ot = 0; ot < 4; ot++) {
                f16x8 bf = *(const f16x8*)(wgt + (size_t)(og*64 + ot*16 + col)*CC + ck*32 + grp*8);
                acc[ot] = __builtin_amdgcn_mfma_f32_16x16x32_f16(af, bf, acc[ot], 0, 0, 0);
            }
        }
        int iw = i0 + grp * 4;
        #pragma unroll
        for (int ot = 0; ot < 4; ot++) {
            int o = og*64 + ot*16 + col;
            float bo = bv[o];
            union { _Float16 h[4]; uint2 u; } pk;
            pk.h[0] = (_Float16)(acc[ot][0] + bo);
            pk.h[1] = (_Float16)(acc[ot][1] + bo);
            pk.h[2] = (_Float16)(acc[ot][2] + bo);
            pk.h[3] = (_Float16)(acc[ot][3] + bo);
            *(uint2*)(outp + (size_t)o*NN + iw) = pk.u;
        }
    }
}

// ------------- Kernel C: flash attention (round-8 structure + isolated SA/SB split) -------------
#define STAGE_K(tt, bb) do { int _j = jlo + (tt)*CH; _Pragma("unroll") \
    for (int e = 0; e < 4; e++) gload16(kb + (size_t)_j*CC + koff[e], &bufK[bb][(4*w + e)*512]); } while (0)
#define STAGE_V(tt, bb) do { int _j = jlo + (tt)*CH; _Pragma("unroll") \
    for (int e = 0; e < 4; e++) gload16(vb + voff[e] + _j, &bufV[bb][(4*w + e)*512]); } while (0)

__global__ __launch_bounds__(256, 2) void attn_kernel(
    const unsigned short* __restrict__ qT,
    const unsigned short* __restrict__ kT,
    const unsigned short* __restrict__ vC,
    unsigned short* __restrict__ pO,
    float2* __restrict__ ml)
{
    int qt = blockIdx.x, s = blockIdx.y, b = blockIdx.z;
    int tid = threadIdx.x, w = tid >> 6, lane = tid & 63;
    int l31 = lane & 31, hi = lane >> 5;
    int col = lane & 15, grp = lane >> 4;
    int q0 = qt * QTILE + w * 32;
    int jlo = s * JBLK;

    __shared__ __align__(16) unsigned short bufK[2][8192];   // 2 x 16 KB
    __shared__ __align__(16) unsigned short bufV[2][8192];   // 2 x 16 KB
    __shared__ __align__(16) unsigned short plds[4 * 1280];  // 4 waves x 32q x 40sh (10 KB)

    const unsigned short* qb = qT + (size_t)b * NN * CC;
    const unsigned short* kb = kT + (size_t)b * NN * CC;
    const unsigned short* vb = vC + (size_t)b * CC * NN;

    // Q fragment: (lane,e) -> c = ck*16 + hi*8 + e  (same assignment as K below)
    f16x8 qf[16];
    #pragma unroll
    for (int ck = 0; ck < 16; ck++)
        qf[ck] = *(const f16x8*)(qb + (size_t)(q0 + l31)*CC + ck*16 + hi*8);

    int koff[4], voff[4];
    #pragma unroll
    for (int e = 0; e < 4; e++) {
        int blk = (4*w + e)*64 + lane;
        int kj = blk >> 5, kcb = blk & 31;
        koff[e] = kj*CC + ((kcb ^ (kj & 7)) * 8);
        int vc = blk >> 2, vcb = blk & 3;
        voff[e] = vc*NN + ((vcb ^ ((vc >> 1) & 3)) * 8);
    }
    int kru = l31 * 512;     // K row byte base (row = j = l31)
    int kx  = l31 & 7;       // K row XOR
    int vrb = col*64 + ((grp ^ ((col >> 1) & 3)) << 4);   // V read (row c=ct*16+col)
    char* pw  = (char*)plds + w*2560 + l31*80 + 8*hi;     // P write base (row q=l31)
    const char* prd = (const char*)plds + w*2560;          // P read base

    f32x4 O0[16], O1[16];
    #pragma unroll
    for (int ct = 0; ct < 16; ct++) {
        O0[ct] = (f32x4){0.f,0.f,0.f,0.f};
        O1[ct] = (f32x4){0.f,0.f,0.f,0.f};
    }
    float m = -1e30f, l = 0.f;

    STAGE_K(0, 0);
    STAGE_V(0, 0);
    __syncthreads();

    for (int t = 0; t < NT; t++) {
        int cur = t & 1;
        if (t + 1 < NT) {
            STAGE_K(t + 1, cur ^ 1);
            STAGE_V(t + 1, cur ^ 1);
        }
        const char* kbase = (const char*)&bufK[cur][0];
        const char* vbase = (const char*)&bufV[cur][0];

        // QK: S[j][q]; K fragment (lane,e) -> c = ck*16 + hi*8 + e (== Q's map).
        // SA/SB: two 8-deep independent MFMA chains (fp32 re-association only).
        f32x16 SA, SB;
        #pragma unroll
        for (int r = 0; r < 16; r++) { SA[r] = 0.f; SB[r] = 0.f; }
        __builtin_amdgcn_s_setprio(1);
        #pragma unroll
        for (int ck = 0; ck < 8; ck++) {
            f16x8 kf0 = *(const f16x8*)(kbase + kru + ((((4*ck)     | hi) ^ kx) << 4));
            f16x8 kf1 = *(const f16x8*)(kbase + kru + ((((4*ck + 2) | hi) ^ kx) << 4));
            SA = __builtin_amdgcn_mfma_f32_32x32x16_f16(kf0, qf[2*ck],     SA, 0, 0, 0);
            SB = __builtin_amdgcn_mfma_f32_32x32x16_f16(kf1, qf[2*ck + 1], SB, 0, 0, 0);
        }
        __builtin_amdgcn_s_setprio(0);
        f32x16 S = SA + SB;

        // per-lane softmax over own 16 j; combine with partner half via shfl_xor 32
        float x0 = fmaxf(fmaxf(S[0], S[1]), fmaxf(S[2], S[3]));
        float x1 = fmaxf(fmaxf(S[4], S[5]), fmaxf(S[6], S[7]));
        float x2 = fmaxf(fmaxf(S[8], S[9]), fmaxf(S[10], S[11]));
        float x3 = fmaxf(fmaxf(S[12], S[13]), fmaxf(S[14], S[15]));
        float mh = fmaxf(fmaxf(x0, x1), fmaxf(x2, x3));
        float mx = fmaxf(mh, __shfl_xor(mh, 32));

        // defer-max: rescale only when max grew by > 8 (exp2 domain)
        if (!__all(mx <= m + 8.f)) {
            float mn = fmaxf(m, mx);
            float f = exp2f(m - mn);
            m = mn;
            l *= f;
            float fq0 = __shfl(f, col);
            float fq1 = __shfl(f, 16 + col);
            #pragma unroll
            for (int ct = 0; ct < 16; ct++) { O0[ct] *= fq0; O1[ct] *= fq1; }
        }

        #pragma unroll
        for (int r = 0; r < 16; r++) S[r] = exp2f(S[r] - m);
        float ps = (((S[0]+S[1]) + (S[2]+S[3])) + ((S[4]+S[5]) + (S[6]+S[7])))
                 + (((S[8]+S[9]) + (S[10]+S[11])) + ((S[12]+S[13]) + (S[14]+S[15])));
        l += ps + __shfl_xor(ps, 32);

        // P -> LDS: own j's only (C-layout row formula j=(r&3)+8*(r>>2)+4*hi)
        {
            unsigned* pr = (unsigned*)pw;
            pr[0]  = pkh2(S[0],  S[1]);   pr[1]  = pkh2(S[2],  S[3]);
            pr[4]  = pkh2(S[4],  S[5]);   pr[5]  = pkh2(S[6],  S[7]);
            pr[8]  = pkh2(S[8],  S[9]);   pr[9]  = pkh2(S[10], S[11]);
            pr[12] = pkh2(S[12], S[13]);  pr[13] = pkh2(S[14], S[15]);
        }
        asm volatile("s_waitcnt lgkmcnt(0)" ::: "memory");
        __builtin_amdgcn_sched_barrier(0);

        // PV via 16x16x32: both fragments (lane,e) -> j = grp*8 + e (cancels)
        f16x8 y0 = *(const f16x8*)(prd + col*80 + grp*16);
        f16x8 y1 = *(const f16x8*)(prd + (16 + col)*80 + grp*16);
        __builtin_amdgcn_s_setprio(1);
        #pragma unroll
        for (int ct = 0; ct < 16; ct++) {
            f16x8 xf = *(const f16x8*)(vbase + ct*1024 + vrb);
            O0[ct] = __builtin_amdgcn_mfma_f32_16x16x32_f16(xf, y0, O0[ct], 0, 0, 0);
            O1[ct] = __builtin_amdgcn_mfma_f32_16x16x32_f16(xf, y1, O1[ct], 0, 0, 0);
        }
        __builtin_amdgcn_s_setprio(0);
        __syncthreads();
    }

    // epilogue: O C-layout (m89): q = qh*16+col, c = ct*16 + grp*4 + r
    float inv = 1.f / l;
    float iq0 = __shfl(inv, col);
    float iq1 = __shfl(inv, 16 + col);
    unsigned short* po = pO + ((size_t)(s*BB + b)*NN + q0) * CC;
    #pragma unroll
    for (int ct = 0; ct < 16; ct++) {
        int c = ct*16 + grp*4;
        *(unsigned*)(po + (size_t)col*CC + c)            = pkh2(O0[ct][0]*iq0, O0[ct][1]*iq0);
        *(unsigned*)(po + (size_t)col*CC + c + 2)        = pkh2(O0[ct][2]*iq0, O0[ct][3]*iq0);
        *(unsigned*)(po + (size_t)(16 + col)*CC + c)     = pkh2(O1[ct][0]*iq1, O1[ct][1]*iq1);
        *(unsigned*)(po + (size_t)(16 + col)*CC + c + 2) = pkh2(O1[ct][2]*iq1, O1[ct][3]*iq1);
    }
    if (lane < 32)
        ml[(size_t)(s*BB + b)*NN + q0 + lane] = make_float2(m, l);
}

// ------------- Kernel D: fused JSPLIT-merge + output projection, 16-row tiles -------------
__global__ __launch_bounds__(256, 2) void proj_out_merge_kernel(
    const unsigned short* __restrict__ pO, const float2* __restrict__ ml,
    const unsigned short* __restrict__ wp16, const float* __restrict__ bp,
    const float* __restrict__ x, float* __restrict__ out)
{
    int b  = blockIdx.y;
    int i0 = blockIdx.x * ITILE;
    int t  = threadIdx.x;
    __shared__ __align__(16) unsigned short htile[ITILE * 256];   // 8 KB, swizzled

    // ---- phase 1: merge (16 threads/row x 16 c each) ----
    {
        int row  = t >> 4;            // 0..15
        int cseg = (t & 15) * 16;     // 16 c per thread
        size_t qrow = (size_t)b * NN + i0 + row;
        float M = -1e30f;
        float m8[JSPLIT], l8[JSPLIT];
        #pragma unroll
        for (int s = 0; s < JSPLIT; s++) {
            float2 v = ml[(size_t)s*BB*NN + qrow];
            m8[s] = v.x; l8[s] = v.y;
            M = fmaxf(M, v.x);
        }
        float W = 0.f, wt[JSPLIT];
        #pragma unroll
        for (int s = 0; s < JSPLIT; s++) { wt[s] = l8[s] * exp2f(m8[s] - M); W += wt[s]; }
        float iW = 1.f / W;
        float acc[16];
        #pragma unroll
        for (int e = 0; e < 16; e++) acc[e] = 0.f;
        #pragma unroll
        for (int s = 0; s < JSPLIT; s++) {
            const unsigned short* p = pO + ((size_t)s*BB*NN + qrow)*CC + cseg;
            float ws = wt[s] * iW;
            #pragma unroll
            for (int k = 0; k < 2; k++) {
                f16x8 a = *(const f16x8*)(p + k*8);
                #pragma unroll
                for (int e = 0; e < 8; e++) acc[k*8 + e] += ws * (float)a[e];
            }
        }
        char* hw = (char*)htile;
        #pragma unroll
        for (int k = 0; k < 2; k++) {
            int c0 = cseg + k*8;
            uint4 pk;
            pk.x = pkh2(acc[k*8+0], acc[k*8+1]);
            pk.y = pkh2(acc[k*8+2], acc[k*8+3]);
            pk.z = pkh2(acc[k*8+4], acc[k*8+5]);
            pk.w = pkh2(acc[k*8+6], acc[k*8+7]);
            int off = row*512 + (((c0 >> 3) ^ (row & 7)) << 4);
            *(uint4*)(hw + off) = pk;
        }
    }
    __syncthreads();

    // ---- phase 2: projection; wave w owns o-group w (64 outputs), all 16 rows ----
    int lane = t & 63, wid = t >> 6;
    int col = lane & 15, grp = lane >> 4;
    const char* hr = (const char*)htile;
    int o0 = wid * 64;
    f32x4 acc[4];
    #pragma unroll
    for (int ot = 0; ot < 4; ot++) acc[ot] = (f32x4){0.f,0.f,0.f,0.f};
    #pragma unroll
    for (int ck = 0; ck < 8; ck++) {
        f16x8 af = *(const f16x8*)(hr + col*512 + (((ck*4 + grp) ^ (col & 7)) << 4));
        #pragma unroll
        for (int ot = 0; ot < 4; ot++) {
            f16x8 bf = *(const f16x8*)(wp16 + (size_t)(o0 + ot*16 + col)*CC + ck*32 + grp*8);
            acc[ot] = __builtin_amdgcn_mfma_f32_16x16x32_f16(af, bf, acc[ot], 0, 0, 0);
        }
    }
    int iw = i0 + grp * 4;
    #pragma unroll
    for (int ot = 0; ot < 4; ot++) {
        int o = o0 + ot*16 + col;
        float bo = bp[o];
        size_t base = (size_t)b*CC*NN + (size_t)o*NN + iw;
        float4 x4 = *(const float4*)(x + base);
        float4 r;
        r.x = x4.x + acc[ot][0] + bo;
        r.y = x4.y + acc[ot][1] + bo;
        r.z = x4.z + acc[ot][2] + bo;
        r.w = x4.w + acc[ot][3] + bo;
        *(float4*)(out + base) = r;
    }
}

extern "C" void kernel_launch(void* const* d_in, const int* in_sizes, int n_in,
                              void* d_out, int out_size, void* d_ws, size_t ws_size,
                              hipStream_t stream) {
    const float* x  = (const float*)d_in[0];
    const float* gs = (const float*)d_in[1];
    const float* gb = (const float*)d_in[2];
    const float* wq = (const float*)d_in[3];
    const float* bq = (const float*)d_in[4];
    const float* wk = (const float*)d_in[5];
    const float* bk = (const float*)d_in[6];
    const float* wv = (const float*)d_in[7];
    const float* bv = (const float*)d_in[8];
    const float* wp = (const float*)d_in[9];
    const float* bp = (const float*)d_in[10];
    float* out = (float*)d_out;

    char* ws = (char*)d_ws;
    const size_t sz = (size_t)BB * NN * CC * sizeof(unsigned short);   // 4 MB
    unsigned short* qT  = (unsigned short*)(ws + sz);
    unsigned short* kT  = (unsigned short*)(ws + 2*sz);
    unsigned short* vC  = (unsigned short*)(ws + 3*sz);
    unsigned short* w16 = (unsigned short*)(ws + 5*sz);                 // 512 KB
    float2* part        = (float2*)(ws + 5*sz + 512*1024);              // 2 KB
    float2* ml          = (float2*)(ws + 5*sz + 768*1024);              // 512 KB
    unsigned short* pO  = (unsigned short*)(ws + 5*sz + 1280*1024);     // 32 MB

    prep_gn_kernel<<<dim3(512), 256, 0, stream>>>(wq, wk, wv, wp, w16, x, part);
    proj_qkv_kernel<<<dim3(NN/16, BB), 256, 0, stream>>>(x, gs, gb, part, w16,
                                                         bq, bk, bv, qT, kT, vC);
    attn_kernel<<<dim3(NN/QTILE, JSPLIT, BB), 256, 0, stream>>>(qT, kT, vC, pO, ml);
    proj_out_merge_kernel<<<dim3(NN/ITILE, BB), 256, 0, stream>>>(pO, ml, w16 + 3*CC*CC,
                                                                  bp, x, out);
}

// Round 16
// 115.306 us; speedup vs baseline: 1.0868x; 1.0868x over previous
//
#include <hip/hip_runtime.h>
#include <hip/hip_bf16.h>
#include <math.h>

#define BB 2
#define CC 256
#define GG 32
#define NN 4096
#define EPSF 1e-6f
#define JSPLIT 8
#define JBLK (NN / JSPLIT)   // 512 j per block
#define CH 32                // j chunk
#define NT (JBLK / CH)       // 16 chunks
#define QTILE 128            // queries per attn block (4 waves x 32)
#define ITILE 16             // i-rows per fused out block (2 blocks/CU)
#define LOG2E 1.4426950408889634f

typedef _Float16 f16x8 __attribute__((ext_vector_type(8)));
typedef float f32x4 __attribute__((ext_vector_type(4)));
typedef float f32x16 __attribute__((ext_vector_type(16)));

static __device__ __forceinline__ unsigned short f2h_bits(float f) {
    _Float16 h = (_Float16)f;
    return __builtin_bit_cast(unsigned short, h);
}
static __device__ __forceinline__ unsigned pkh2(float a, float b) {
    return __builtin_bit_cast(unsigned, __builtin_amdgcn_cvt_pkrtz(a, b));
}
static __device__ __forceinline__ void gload16(const void* g, void* l) {
    __builtin_amdgcn_global_load_lds(
        (const __attribute__((address_space(1))) void*)g,
        (__attribute__((address_space(3))) void*)l, 16, 0, 0);
}

// ------- Kernel A: fused weight->fp16 conversion (blocks 0..255) + GN partials (256..511) -------
__global__ __launch_bounds__(256) void prep_gn_kernel(
    const float* __restrict__ wq, const float* __restrict__ wk,
    const float* __restrict__ wv, const float* __restrict__ wp,
    unsigned short* __restrict__ w16,
    const float* __restrict__ x, float2* __restrict__ part)
{
    __shared__ float red[8];
    int id = blockIdx.x;
    int t  = threadIdx.x;
    if (id < 256) {
        int m = id >> 6;
        const float* src = (m == 0) ? wq : (m == 1) ? wk : (m == 2) ? wv : wp;
        float scale = (m == 0) ? 0.0625f * LOG2E : 1.0f;
        int idx = (id & 63) * 256 + t;   // unit = 4 floats
        float4 v = ((const float4*)src)[idx];
        union { _Float16 h[4]; uint2 u; } pk;
        pk.h[0] = (_Float16)(v.x * scale);
        pk.h[1] = (_Float16)(v.y * scale);
        pk.h[2] = (_Float16)(v.z * scale);
        pk.h[3] = (_Float16)(v.w * scale);
        *(uint2*)(w16 + (size_t)m * CC * CC + (size_t)idx * 4) = pk.u;
    } else {
        int rem = id - 256;
        int g = rem & 31, p = (rem >> 5) & 3, b = rem >> 7;
        const float* base = x + ((size_t)b * CC + (size_t)g * 8) * NN + (size_t)p * 8192;
        float s = 0.f, ss = 0.f;
        for (int idx = t; idx < 2048; idx += 256) {
            float4 v4 = ((const float4*)base)[idx];
            s  += v4.x + v4.y + v4.z + v4.w;
            ss += v4.x*v4.x + v4.y*v4.y + v4.z*v4.z + v4.w*v4.w;
        }
        for (int off = 32; off; off >>= 1) {
            s  += __shfl_down(s,  off);
            ss += __shfl_down(ss, off);
        }
        int wid = t >> 6;
        if ((t & 63) == 0) { red[wid*2] = s; red[wid*2+1] = ss; }
        __syncthreads();
        if (t == 0) {
            part[(b*GG + g)*4 + p] = make_float2(red[0]+red[2]+red[4]+red[6],
                                                 red[1]+red[3]+red[5]+red[7]);
        }
    }
}

// ------------- Kernel B: fused GN-apply + q/k/v projections, 16-row tiles (2 blocks/CU) -------------
__global__ __launch_bounds__(256) void proj_qkv_kernel(
    const float* __restrict__ x, const float* __restrict__ sc,
    const float* __restrict__ bi, const float2* __restrict__ part,
    const unsigned short* __restrict__ w16,
    const float* __restrict__ bq, const float* __restrict__ bk,
    const float* __restrict__ bv,
    unsigned short* __restrict__ qT, unsigned short* __restrict__ kT,
    unsigned short* __restrict__ vC)
{
    int b  = blockIdx.y;
    int i0 = blockIdx.x * 16;
    int t  = threadIdx.x;
    __shared__ unsigned short htile[16 * 256];   // 8 KB, swizzled
    __shared__ float s_mean[GG], s_rstd[GG], s_sc[CC], s_bi[CC];
    if (t < GG) {
        float2 p0 = part[(b*GG + t)*4 + 0];
        float2 p1 = part[(b*GG + t)*4 + 1];
        float2 p2 = part[(b*GG + t)*4 + 2];
        float2 p3 = part[(b*GG + t)*4 + 3];
        float S  = p0.x + p1.x + p2.x + p3.x;
        float SS = p0.y + p1.y + p2.y + p3.y;
        float mean = S / 32768.f;
        float var  = SS / 32768.f - mean * mean;
        s_mean[t] = mean;
        s_rstd[t] = rsqrtf(var + EPSF);
    }
    s_sc[t] = sc[t];
    s_bi[t] = bi[t];
    __syncthreads();

    // fill: one 4x4 quad-tile per thread (16 rows x 256 c total)
    char* hw = (char*)htile;
    {
        int nq = (t & 3) * 4;
        int c0 = (t >> 2) * 4;
        float4 xr[4];
        float aa[4], dd[4];
        #pragma unroll
        for (int e = 0; e < 4; e++) {
            int c = c0 + e;
            xr[e] = *(const float4*)(x + ((size_t)b*CC + c)*NN + i0 + nq);
            aa[e] = s_rstd[c >> 3] * s_sc[c];
            dd[e] = s_bi[c] - s_mean[c >> 3] * aa[e];
        }
        #pragma unroll
        for (int j = 0; j < 4; j++) {
            int row = nq + j;
            union { _Float16 h[4]; uint2 u; } pk;
            pk.h[0] = (_Float16)(((const float*)&xr[0])[j] * aa[0] + dd[0]);
            pk.h[1] = (_Float16)(((const float*)&xr[1])[j] * aa[1] + dd[1]);
            pk.h[2] = (_Float16)(((const float*)&xr[2])[j] * aa[2] + dd[2]);
            pk.h[3] = (_Float16)(((const float*)&xr[3])[j] * aa[3] + dd[3]);
            int off = row*512 + (((c0 >> 3) ^ (row & 7)) << 4) + (c0 & 7) * 2;
            *(uint2*)(hw + off) = pk.u;
        }
    }
    __syncthreads();

    int lane = t & 63, w = t >> 6;
    int col = lane & 15, grp = lane >> 4;
    const char* hr = (const char*)htile;
    int rowc = col;   // A-tile row for MFMA fragments (16 rows)

    // q, k: wave w owns o-subtile ot*64 + w*16
    #pragma unroll
    for (int p = 0; p < 2; p++) {
        const unsigned short* wgt = w16 + (size_t)p * CC * CC;
        const float* bias = p ? bk : bq;
        unsigned short* outp = (p ? kT : qT) + (size_t)b * NN * CC;
        float osc = p ? 1.0f : 0.0625f * LOG2E;
        #pragma unroll
        for (int ot = 0; ot < 4; ot++) {
            int ow = ot * 64 + w * 16;
            f32x4 acc = (f32x4){0.f,0.f,0.f,0.f};
            #pragma unroll
            for (int ck = 0; ck < 8; ck++) {
                f16x8 af = *(const f16x8*)(wgt + (size_t)(ow + col)*CC + ck*32 + grp*8);
                f16x8 bf = *(const f16x8*)(hr + rowc*512 + (((ck*4 + grp) ^ (rowc & 7)) << 4));
                acc = __builtin_amdgcn_mfma_f32_16x16x32_f16(af, bf, acc, 0, 0, 0);
            }
            int obase = ow + grp * 4;
            float b0 = bias[obase]*osc, b1 = bias[obase+1]*osc,
                  b2 = bias[obase+2]*osc, b3 = bias[obase+3]*osc;
            int i = i0 + col;
            union { _Float16 h[4]; uint2 u; } pk;
            pk.h[0] = (_Float16)(acc[0] + b0);
            pk.h[1] = (_Float16)(acc[1] + b1);
            pk.h[2] = (_Float16)(acc[2] + b2);
            pk.h[3] = (_Float16)(acc[3] + b3);
            *(uint2*)(outp + (size_t)i*CC + obase) = pk.u;
        }
    }
    // v: wave w owns o-group w (64 outputs), all 16 rows
    {
        const unsigned short* wgt = w16 + (size_t)2 * CC * CC;
        unsigned short* outp = vC + (size_t)b * CC * NN;
        int og = w;
        f32x4 acc[4];
        #pragma unroll
        for (int ot = 0; ot < 4; ot++) acc[ot] = (f32x4){0.f,0.f,0.f,0.f};
        #pragma unroll
        for (int ck = 0; ck < 8; ck++) {
            f16x8 af = *(const f16x8*)(hr + rowc*512 + (((ck*4 + grp) ^ (rowc & 7)) << 4));
            #pragma unroll
            for (int ot = 0; ot < 4; ot++) {
                f16x8 bf = *(const f16x8*)(wgt + (size_t)(og*64 + ot*16 + col)*CC + ck*32 + grp*8);
                acc[ot] = __builtin_amdgcn_mfma_f32_16x16x32_f16(af, bf, acc[ot], 0, 0, 0);
            }
        }
        int iw = i0 + grp * 4;
        #pragma unroll
        for (int ot = 0; ot < 4; ot++) {
            int o = og*64 + ot*16 + col;
            float bo = bv[o];
            union { _Float16 h[4]; uint2 u; } pk;
            pk.h[0] = (_Float16)(acc[ot][0] + bo);
            pk.h[1] = (_Float16)(acc[ot][1] + bo);
            pk.h[2] = (_Float16)(acc[ot][2] + bo);
            pk.h[3] = (_Float16)(acc[ot][3] + bo);
            *(uint2*)(outp + (size_t)o*NN + iw) = pk.u;
        }
    }
}

// ------------- Kernel C: flash attention (round-8 verified kernel, 67.5us) -------------
#define STAGE_K(tt, bb) do { int _j = jlo + (tt)*CH; _Pragma("unroll") \
    for (int e = 0; e < 4; e++) gload16(kb + (size_t)_j*CC + koff[e], &bufK[bb][(4*w + e)*512]); } while (0)
#define STAGE_V(tt, bb) do { int _j = jlo + (tt)*CH; _Pragma("unroll") \
    for (int e = 0; e < 4; e++) gload16(vb + voff[e] + _j, &bufV[bb][(4*w + e)*512]); } while (0)

__global__ __launch_bounds__(256, 2) void attn_kernel(
    const unsigned short* __restrict__ qT,
    const unsigned short* __restrict__ kT,
    const unsigned short* __restrict__ vC,
    unsigned short* __restrict__ pO,
    float2* __restrict__ ml)
{
    int qt = blockIdx.x, s = blockIdx.y, b = blockIdx.z;
    int tid = threadIdx.x, w = tid >> 6, lane = tid & 63;
    int l31 = lane & 31, hi = lane >> 5;
    int col = lane & 15, grp = lane >> 4;
    int q0 = qt * QTILE + w * 32;
    int jlo = s * JBLK;

    __shared__ __align__(16) unsigned short bufK[2][8192];   // 2 x 16 KB
    __shared__ __align__(16) unsigned short bufV[2][8192];   // 2 x 16 KB
    __shared__ __align__(16) unsigned short plds[4 * 1280];  // 4 waves x 32q x 40sh (10 KB)

    const unsigned short* qb = qT + (size_t)b * NN * CC;
    const unsigned short* kb = kT + (size_t)b * NN * CC;
    const unsigned short* vb = vC + (size_t)b * CC * NN;

    // Q fragment: (lane,e) -> c = ck*16 + hi*8 + e  (same assignment as K below)
    f16x8 qf[16];
    #pragma unroll
    for (int ck = 0; ck < 16; ck++)
        qf[ck] = *(const f16x8*)(qb + (size_t)(q0 + l31)*CC + ck*16 + hi*8);

    int koff[4], voff[4];
    #pragma unroll
    for (int e = 0; e < 4; e++) {
        int blk = (4*w + e)*64 + lane;
        int kj = blk >> 5, kcb = blk & 31;
        koff[e] = kj*CC + ((kcb ^ (kj & 7)) * 8);
        int vc = blk >> 2, vcb = blk & 3;
        voff[e] = vc*NN + ((vcb ^ ((vc >> 1) & 3)) * 8);
    }
    int kru = l31 * 512;     // K row byte base (row = j = l31)
    int kx  = l31 & 7;       // K row XOR
    int vrb = col*64 + ((grp ^ ((col >> 1) & 3)) << 4);   // V read (row c=ct*16+col)
    char* pw  = (char*)plds + w*2560 + l31*80 + 8*hi;     // P write base (row q=l31)
    const char* prd = (const char*)plds + w*2560;          // P read base

    f32x4 O0[16], O1[16];
    #pragma unroll
    for (int ct = 0; ct < 16; ct++) {
        O0[ct] = (f32x4){0.f,0.f,0.f,0.f};
        O1[ct] = (f32x4){0.f,0.f,0.f,0.f};
    }
    float m = -1e30f, l = 0.f;

    STAGE_K(0, 0);
    STAGE_V(0, 0);
    __syncthreads();

    for (int t = 0; t < NT; t++) {
        int cur = t & 1;
        if (t + 1 < NT) {
            STAGE_K(t + 1, cur ^ 1);
            STAGE_V(t + 1, cur ^ 1);
        }
        const char* kbase = (const char*)&bufK[cur][0];
        const char* vbase = (const char*)&bufV[cur][0];

        // QK: S[j][q]; K fragment (lane,e) -> c = ck*16 + hi*8 + e (== Q's map)
        f32x16 S;
        #pragma unroll
        for (int r = 0; r < 16; r++) S[r] = 0.f;
        __builtin_amdgcn_s_setprio(1);
        #pragma unroll
        for (int ck = 0; ck < 16; ck++) {
            f16x8 kf = *(const f16x8*)(kbase + kru + ((((ck*2) | hi) ^ kx) << 4));
            S = __builtin_amdgcn_mfma_f32_32x32x16_f16(kf, qf[ck], S, 0, 0, 0);
        }
        __builtin_amdgcn_s_setprio(0);

        // per-lane softmax over own 16 j; combine with partner half via shfl_xor 32
        float x0 = fmaxf(fmaxf(S[0], S[1]), fmaxf(S[2], S[3]));
        float x1 = fmaxf(fmaxf(S[4], S[5]), fmaxf(S[6], S[7]));
        float x2 = fmaxf(fmaxf(S[8], S[9]), fmaxf(S[10], S[11]));
        float x3 = fmaxf(fmaxf(S[12], S[13]), fmaxf(S[14], S[15]));
        float mh = fmaxf(fmaxf(x0, x1), fmaxf(x2, x3));
        float mx = fmaxf(mh, __shfl_xor(mh, 32));

        // defer-max: rescale only when max grew by > 8 (exp2 domain)
        if (!__all(mx <= m + 8.f)) {
            float mn = fmaxf(m, mx);
            float f = exp2f(m - mn);
            m = mn;
            l *= f;
            float fq0 = __shfl(f, col);
            float fq1 = __shfl(f, 16 + col);
            #pragma unroll
            for (int ct = 0; ct < 16; ct++) { O0[ct] *= fq0; O1[ct] *= fq1; }
        }

        #pragma unroll
        for (int r = 0; r < 16; r++) S[r] = exp2f(S[r] - m);
        float ps = (((S[0]+S[1]) + (S[2]+S[3])) + ((S[4]+S[5]) + (S[6]+S[7])))
                 + (((S[8]+S[9]) + (S[10]+S[11])) + ((S[12]+S[13]) + (S[14]+S[15])));
        l += ps + __shfl_xor(ps, 32);

        // P -> LDS: own j's only (C-layout row formula j=(r&3)+8*(r>>2)+4*hi)
        {
            unsigned* pr = (unsigned*)pw;
            pr[0]  = pkh2(S[0],  S[1]);   pr[1]  = pkh2(S[2],  S[3]);
            pr[4]  = pkh2(S[4],  S[5]);   pr[5]  = pkh2(S[6],  S[7]);
            pr[8]  = pkh2(S[8],  S[9]);   pr[9]  = pkh2(S[10], S[11]);
            pr[12] = pkh2(S[12], S[13]);  pr[13] = pkh2(S[14], S[15]);
        }
        asm volatile("s_waitcnt lgkmcnt(0)" ::: "memory");
        __builtin_amdgcn_sched_barrier(0);

        // PV via 16x16x32: both fragments (lane,e) -> j = grp*8 + e (cancels)
        f16x8 y0 = *(const f16x8*)(prd + col*80 + grp*16);
        f16x8 y1 = *(const f16x8*)(prd + (16 + col)*80 + grp*16);
        __builtin_amdgcn_s_setprio(1);
        #pragma unroll
        for (int ct = 0; ct < 16; ct++) {
            f16x8 xf = *(const f16x8*)(vbase + ct*1024 + vrb);
            O0[ct] = __builtin_amdgcn_mfma_f32_16x16x32_f16(xf, y0, O0[ct], 0, 0, 0);
            O1[ct] = __builtin_amdgcn_mfma_f32_16x16x32_f16(xf, y1, O1[ct], 0, 0, 0);
        }
        __builtin_amdgcn_s_setprio(0);
        __syncthreads();
    }

    // epilogue: O C-layout (m89): q = qh*16+col, c = ct*16 + grp*4 + r
    float inv = 1.f / l;
    float iq0 = __shfl(inv, col);
    float iq1 = __shfl(inv, 16 + col);
    unsigned short* po = pO + ((size_t)(s*BB + b)*NN + q0) * CC;
    #pragma unroll
    for (int ct = 0; ct < 16; ct++) {
        int c = ct*16 + grp*4;
        *(unsigned*)(po + (size_t)col*CC + c)            = pkh2(O0[ct][0]*iq0, O0[ct][1]*iq0);
        *(unsigned*)(po + (size_t)col*CC + c + 2)        = pkh2(O0[ct][2]*iq0, O0[ct][3]*iq0);
        *(unsigned*)(po + (size_t)(16 + col)*CC + c)     = pkh2(O1[ct][0]*iq1, O1[ct][1]*iq1);
        *(unsigned*)(po + (size_t)(16 + col)*CC + c + 2) = pkh2(O1[ct][2]*iq1, O1[ct][3]*iq1);
    }
    if (lane < 32)
        ml[(size_t)(s*BB + b)*NN + q0 + lane] = make_float2(m, l);
}

// ------------- Kernel D: fused JSPLIT-merge + output projection, 16-row tiles -------------
__global__ __launch_bounds__(256, 2) void proj_out_merge_kernel(
    const unsigned short* __restrict__ pO, const float2* __restrict__ ml,
    const unsigned short* __restrict__ wp16, const float* __restrict__ bp,
    const float* __restrict__ x, float* __restrict__ out)
{
    int b  = blockIdx.y;
    int i0 = blockIdx.x * ITILE;
    int t  = threadIdx.x;
    __shared__ __align__(16) unsigned short htile[ITILE * 256];   // 8 KB, swizzled

    // ---- phase 1: merge (16 threads/row x 16 c each) ----
    {
        int row  = t >> 4;            // 0..15
        int cseg = (t & 15) * 16;     // 16 c per thread
        size_t qrow = (size_t)b * NN + i0 + row;
        float M = -1e30f;
        float m8[JSPLIT], l8[JSPLIT];
        #pragma unroll
        for (int s = 0; s < JSPLIT; s++) {
            float2 v = ml[(size_t)s*BB*NN + qrow];
            m8[s] = v.x; l8[s] = v.y;
            M = fmaxf(M, v.x);
        }
        float W = 0.f, wt[JSPLIT];
        #pragma unroll
        for (int s = 0; s < JSPLIT; s++) { wt[s] = l8[s] * exp2f(m8[s] - M); W += wt[s]; }
        float iW = 1.f / W;
        float acc[16];
        #pragma unroll
        for (int e = 0; e < 16; e++) acc[e] = 0.f;
        #pragma unroll
        for (int s = 0; s < JSPLIT; s++) {
            const unsigned short* p = pO + ((size_t)s*BB*NN + qrow)*CC + cseg;
            float ws = wt[s] * iW;
            #pragma unroll
            for (int k = 0; k < 2; k++) {
                f16x8 a = *(const f16x8*)(p + k*8);
                #pragma unroll
                for (int e = 0; e < 8; e++) acc[k*8 + e] += ws * (float)a[e];
            }
        }
        char* hw = (char*)htile;
        #pragma unroll
        for (int k = 0; k < 2; k++) {
            int c0 = cseg + k*8;
            uint4 pk;
            pk.x = pkh2(acc[k*8+0], acc[k*8+1]);
            pk.y = pkh2(acc[k*8+2], acc[k*8+3]);
            pk.z = pkh2(acc[k*8+4], acc[k*8+5]);
            pk.w = pkh2(acc[k*8+6], acc[k*8+7]);
            int off = row*512 + (((c0 >> 3) ^ (row & 7)) << 4);
            *(uint4*)(hw + off) = pk;
        }
    }
    __syncthreads();

    // ---- phase 2: projection; wave w owns o-group w (64 outputs), all 16 rows ----
    int lane = t & 63, wid = t >> 6;
    int col = lane & 15, grp = lane >> 4;
    const char* hr = (const char*)htile;
    int o0 = wid * 64;
    f32x4 acc[4];
    #pragma unroll
    for (int ot = 0; ot < 4; ot++) acc[ot] = (f32x4){0.f,0.f,0.f,0.f};
    #pragma unroll
    for (int ck = 0; ck < 8; ck++) {
        f16x8 af = *(const f16x8*)(hr + col*512 + (((ck*4 + grp) ^ (col & 7)) << 4));
        #pragma unroll
        for (int ot = 0; ot < 4; ot++) {
            f16x8 bf = *(const f16x8*)(wp16 + (size_t)(o0 + ot*16 + col)*CC + ck*32 + grp*8);
            acc[ot] = __builtin_amdgcn_mfma_f32_16x16x32_f16(af, bf, acc[ot], 0, 0, 0);
        }
    }
    int iw = i0 + grp * 4;
    #pragma unroll
    for (int ot = 0; ot < 4; ot++) {
        int o = o0 + ot*16 + col;
        float bo = bp[o];
        size_t base = (size_t)b*CC*NN + (size_t)o*NN + iw;
        float4 x4 = *(const float4*)(x + base);
        float4 r;
        r.x = x4.x + acc[ot][0] + bo;
        r.y = x4.y + acc[ot][1] + bo;
        r.z = x4.z + acc[ot][2] + bo;
        r.w = x4.w + acc[ot][3] + bo;
        *(float4*)(out + base) = r;
    }
}

extern "C" void kernel_launch(void* const* d_in, const int* in_sizes, int n_in,
                              void* d_out, int out_size, void* d_ws, size_t ws_size,
                              hipStream_t stream) {
    const float* x  = (const float*)d_in[0];
    const float* gs = (const float*)d_in[1];
    const float* gb = (const float*)d_in[2];
    const float* wq = (const float*)d_in[3];
    const float* bq = (const float*)d_in[4];
    const float* wk = (const float*)d_in[5];
    const float* bk = (const float*)d_in[6];
    const float* wv = (const float*)d_in[7];
    const float* bv = (const float*)d_in[8];
    const float* wp = (const float*)d_in[9];
    const float* bp = (const float*)d_in[10];
    float* out = (float*)d_out;

    char* ws = (char*)d_ws;
    const size_t sz = (size_t)BB * NN * CC * sizeof(unsigned short);   // 4 MB
    unsigned short* qT  = (unsigned short*)(ws + sz);
    unsigned short* kT  = (unsigned short*)(ws + 2*sz);
    unsigned short* vC  = (unsigned short*)(ws + 3*sz);
    unsigned short* w16 = (unsigned short*)(ws + 5*sz);                 // 512 KB
    float2* part        = (float2*)(ws + 5*sz + 512*1024);              // 2 KB
    float2* ml          = (float2*)(ws + 5*sz + 768*1024);              // 512 KB
    unsigned short* pO  = (unsigned short*)(ws + 5*sz + 1280*1024);     // 32 MB

    prep_gn_kernel<<<dim3(512), 256, 0, stream>>>(wq, wk, wv, wp, w16, x, part);
    proj_qkv_kernel<<<dim3(NN/16, BB), 256, 0, stream>>>(x, gs, gb, part, w16,
                                                         bq, bk, bv, qT, kT, vC);
    attn_kernel<<<dim3(NN/QTILE, JSPLIT, BB), 256, 0, stream>>>(qT, kT, vC, pO, ml);
    proj_out_merge_kernel<<<dim3(NN/ITILE, BB), 256, 0, stream>>>(pO, ml, w16 + 3*CC*CC,
                                                                  bp, x, out);
}